// Round 7
// baseline (386.610 us; speedup 1.0000x reference)
//
#include <hip/hip_runtime.h>

// LengthRegulator: out[b,d,m] = x[b, d, idx[b,m]] * path[b, idx[b,m], m]
// (path one-hot along text axis, idx sorted along m).
//
// K1: idx[m] is the m-th order statistic of 4096 uniforms over [0,512)
//     => idx[m] ~ m/8, sigma ~4. ONE group of 48 outstanding loads covers
//     [m/8-20, m/8+28) (~+-5 sigma beyond the wave's idx span) => a single
//     vmcnt round-trip. Full-rescan fallback keeps correctness for any input.
// K2: block = (b, 2 d-rows) writes a CONTIGUOUS 32 KB slab. All vmem loads
//     happen before one barrier; after it the store stream is fed purely from
//     LDS/registers: no vmcnt waits among stores (vmcnt counts loads+stores
//     in order -- any load-wait inside a store stream also drains all older
//     stores). Plain stores (not nontemporal): L2 acks and drains to HBM
//     asynchronously, like the 6.5 TB/s fillBuffer dispatches.

#define BATCH   32
#define DIM     384
#define T_TEXT  512
#define T_MEL   4096
#define WIN     48    // K1 window rows (single round-trip)
#define ROWS    2     // d-rows per K2 block (32 KB contiguous output slab)

typedef float nfloat4 __attribute__((ext_vector_type(4)));

__global__ __launch_bounds__(256) void find_idx_kernel(
    const float* __restrict__ path,    // [B, T_TEXT, T_MEL]
    int*   __restrict__ idx_ws,        // [B, T_MEL]
    float* __restrict__ scale_ws)      // [B, T_MEL]
{
    const int b = blockIdx.y;
    const int m = blockIdx.x * 256 + threadIdx.x;
    const float* pcol = path + (size_t)b * T_TEXT * T_MEL + m;

    // wave-uniform window start: wave's idx span is ~[base, base+8], dev ~4sigma<18
    int start = ((m & ~63) >> 3) - 20;
    if (start < 0) start = 0;
    if (start > T_TEXT - WIN) start = T_TEXT - WIN;

    int   idx   = 0;
    float scale = 0.0f;
    bool  found = false;

    float v[WIN];
    #pragma unroll
    for (int j = 0; j < WIN; ++j)       // 48 loads in flight, ONE drain
        v[j] = pcol[(size_t)(start + j) * T_MEL];
    #pragma unroll
    for (int j = 0; j < WIN; ++j)
        if (v[j] != 0.0f) { idx = start + j; scale = v[j]; found = true; }

    if (!__all(found)) {                // guaranteed-correct fallback (rare)
        for (int n = 0; n < T_TEXT; n += 16) {
            float u[16];
            #pragma unroll
            for (int j = 0; j < 16; ++j) u[j] = pcol[(size_t)(n + j) * T_MEL];
            #pragma unroll
            for (int j = 0; j < 16; ++j)
                if (!found && u[j] != 0.0f) { idx = n + j; scale = u[j]; found = true; }
            if (__all(found)) break;
        }
    }
    idx_ws[b * T_MEL + m]   = idx;
    scale_ws[b * T_MEL + m] = scale;
}

__global__ __launch_bounds__(256) void gather_kernel(
    const float* __restrict__ x,        // [B, D, T_TEXT]
    const int*   __restrict__ idx_ws,   // [B, T_MEL]
    const float* __restrict__ scale_ws, // [B, T_MEL]
    float* __restrict__ out)            // [B, D, T_MEL]
{
    const int dg = blockIdx.x;          // d-group (2 rows)
    const int b  = blockIdx.y;
    const int t  = threadIdx.x;

    __shared__ float xs[ROWS * T_TEXT]; // 4 KB: the block's 2 x-rows

    // ---- all vmem loads up front ----------------------------------------
    const float* xr = x + ((size_t)b * DIM + dg * ROWS) * T_TEXT;
    const nfloat4 xstage = *(const nfloat4*)(xr + t * 4);   // 2 rows = 1024 floats

    const int*   ip = idx_ws   + b * T_MEL;
    const float* sp = scale_ws + b * T_MEL;
    int4   i4[4];
    float4 s4[4];
    #pragma unroll
    for (int s = 0; s < 4; ++s) {       // this thread's 16 columns (4 sweeps)
        const int m4 = s * 1024 + t * 4;
        i4[s] = *(const int4*)  (ip + m4);
        s4[s] = *(const float4*)(sp + m4);
    }
    *(nfloat4*)(xs + t * 4) = xstage;
    __syncthreads();

    // ---- pure LDS-fed store stream: NO vmem loads past this point --------
    float* ob = out + ((size_t)b * DIM + dg * ROWS) * T_MEL;
    #pragma unroll
    for (int r = 0; r < ROWS; ++r) {
        const float* xsr = xs + r * T_TEXT;
        #pragma unroll
        for (int s = 0; s < 4; ++s) {
            const int m4 = s * 1024 + t * 4;
            nfloat4 o;
            o.x = xsr[i4[s].x] * s4[s].x;   // clustered idx -> LDS broadcast
            o.y = xsr[i4[s].y] * s4[s].y;
            o.z = xsr[i4[s].z] * s4[s].z;
            o.w = xsr[i4[s].w] * s4[s].w;
            *(nfloat4*)(ob + (size_t)r * T_MEL + m4) = o;   // plain store: L2-buffered
        }
    }
}

extern "C" void kernel_launch(void* const* d_in, const int* in_sizes, int n_in,
                              void* d_out, int out_size, void* d_ws, size_t ws_size,
                              hipStream_t stream) {
    (void)in_sizes; (void)n_in; (void)ws_size; (void)out_size;
    const float* x    = (const float*)d_in[0];   // [32, 384, 512]
    const float* path = (const float*)d_in[1];   // [32, 512, 4096]
    float*       out  = (float*)d_out;           // [32, 384, 4096]

    int*   idx_ws   = (int*)d_ws;                          // 512 KB
    float* scale_ws = (float*)((char*)d_ws + (size_t)BATCH * T_MEL * sizeof(int));

    dim3 g1(T_MEL / 256, BATCH);          // 512 blocks, single-round-trip scan
    find_idx_kernel<<<g1, dim3(256), 0, stream>>>(path, idx_ws, scale_ws);

    dim3 g2(DIM / ROWS, BATCH);           // 6144 blocks, 24/CU
    gather_kernel<<<g2, dim3(256), 0, stream>>>(x, idx_ws, scale_ws, out);
}